// Round 1
// 344.816 us; speedup vs baseline: 1.0695x; 1.0695x over previous
//
#include <hip/hip_runtime.h>

// QuadNeighborhoodEncoderDeepsets on gfx950 — round 4.
// VALU-count attack: swapped-operand layer-1 MFMA (lane holds 4 consecutive
// h1-cols -> b64 packed stores), direct global->frag x loads (stage phase +
// barrier removed), v_cvt_pk_bf16_f32 packing, bias fused into exp2 fma,
// ht-store->mean barrier dropped (wave reads only its own cols). 5->3
// barriers/tile. B1f demoted to per-tile L1 reload to protect the 256-reg
// (2 waves/SIMD) unified budget.

#define HID     256
#define OBSD    54
#define SELFD   18
#define TILE_B  8
#define TILE_R  48            // 8 batches * 6 neighbors
#define LDA     264           // A-tile row stride (shorts), 16B-aligned rows
#define LDH     54            // hT col stride (shorts): 27 dwords (odd -> no conflicts)
#define BATCHN  131072
#define NTILES  (BATCHN / TILE_B)
#define GRID_WG 2048
#define TANH_K  2.8853900817779268f   // 2/ln2

typedef __attribute__((ext_vector_type(8))) short bf16x8;   // 4 VGPRs
typedef __attribute__((ext_vector_type(4))) float f32x4;

// pack two f32 -> one dword of 2 bf16 (RNE), single VALU op
__device__ __forceinline__ unsigned cvt_pk_bf16(float lo, float hi) {
    unsigned r;
    asm("v_cvt_pk_bf16_f32 %0, %1, %2" : "=v"(r) : "v"(lo), "v"(hi));
    return r;
}

// tanh(x+b) = 1 - 2/(exp2((x+b)*2/ln2)+1), bias pre-scaled by 2/ln2:
// fma + exp2 + add + rcp + fma  (3 VALU + 2 trans)
__device__ __forceinline__ float tanh_fused(float x, float bK) {
    float t = __builtin_amdgcn_exp2f(__builtin_fmaf(x, TANH_K, bK));
    return 1.0f - 2.0f * __builtin_amdgcn_rcpf(t + 1.0f);
}

// fp32 -> bf16 bits (RNE) — prep kernel only
__device__ __forceinline__ unsigned bfbits(float f) {
    unsigned u = __float_as_uint(f);
    u += 0x7fffu + ((u >> 16) & 1u);
    return u >> 16;
}

// w2t[n][k] = bf16(W2[k][n])  (256x256)
// w1t[n][k] = k<6 ? bf16(W1[k][n]) : 0   (256x32, K zero-padded)
__global__ void prep(const float* __restrict__ W1, const float* __restrict__ W2,
                     short* __restrict__ w1t, short* __restrict__ w2t) {
    int idx = blockIdx.x * 256 + threadIdx.x;
    if (idx < 65536) {
        int n = idx >> 8, k = idx & 255;
        w2t[idx] = (short)bfbits(W2[k * HID + n]);
    } else {
        int j = idx - 65536;
        int n = j >> 5, k = j & 31;
        w1t[j] = (k < 6) ? (short)bfbits(W1[k * HID + n]) : (short)0;
    }
}

__global__ __launch_bounds__(256, 2) void qenc_main(
        const float* __restrict__ obs,
        const short* __restrict__ w1t,
        const float* __restrict__ b1,
        const short* __restrict__ w2t,
        const float* __restrict__ b2,
        float* __restrict__ out)
{
    __shared__ union {
        short a[TILE_R * LDA];    // 25344 B : bf16 h1 (A-tile, row-major)
        short ht[HID * LDH];      // 27648 B : bf16 h2 transposed [col][row]
    } u;

    const int tid  = threadIdx.x;
    const int wave = tid >> 6;
    const int lane = tid & 63;
    const int q    = lane >> 4;
    const int c16  = lane & 15;
    const int colbase = wave * 64;    // this wave's 64-column slice

    // ---- persistent fragments / constants (loaded once per workgroup) ----
    // B layout for 16x16x32: lane holds B[k=q*8+j][n=lane&15].
    bf16x8 Bf[8][4];                  // W2^T: 128 regs
    #pragma unroll
    for (int kk = 0; kk < 8; ++kk)
        #pragma unroll
        for (int ct = 0; ct < 4; ++ct)
            Bf[kk][ct] = *(const bf16x8*)
                (w2t + (colbase + ct * 16 + c16) * HID + kk * 32 + q * 8);

    // layer-1 swapped-MFMA: lane's 4 output cols are colbase+ct*16+q*4+g
    float b1s[4][4];
    #pragma unroll
    for (int ct = 0; ct < 4; ++ct)
        #pragma unroll
        for (int g = 0; g < 4; ++g)
            b1s[ct][g] = b1[colbase + ct * 16 + q * 4 + g] * TANH_K;
    float b2s[4];
    #pragma unroll
    for (int ct = 0; ct < 4; ++ct)
        b2s[ct] = b2[colbase + ct * 16 + c16] * TANH_K;

    // per-lane x source offsets (constant across tiles): row = rt*16+c16
    int soff[3];
    #pragma unroll
    for (int rt = 0; rt < 3; ++rt) {
        int row = rt * 16 + c16;
        soff[rt] = (row / 6) * OBSD + SELFD + (row % 6) * 6;
    }

    for (int tile = blockIdx.x; tile < NTILES; tile += GRID_WG) {
        const size_t obase = (size_t)tile * (TILE_B * OBSD);

        // W1^T frags, per tile (L1-hot after first iter; keeps reg budget <=256)
        bf16x8 B1f[4];
        #pragma unroll
        for (int ct = 0; ct < 4; ++ct)
            B1f[ct] = *(const bf16x8*)(w1t + (colbase + ct * 16 + c16) * 32 + q * 8);

        // ---- layer 1: h1 = tanh(x @ W1 + b1), swapped operands ----
        // mfma(W1T-as-A, x-as-B): D[m=h1col][n=h1row]; lane holds
        // rows = rt*16+c16, cols = colbase+ct*16+q*4+g  (4 consecutive!)
        #pragma unroll
        for (int rt = 0; rt < 3; ++rt) {
            // all lanes load the same row's 6 floats (q-redundant; coalescer
            // merges same-address lanes). k=6..31 hit zero rows of w1t, so
            // garbage there is harmless — but keep word3 = 0 (finite).
            const float* src = obs + obase + soff[rt];
            float2 f0 = *(const float2*)(src);
            float2 f1 = *(const float2*)(src + 2);
            float2 f2 = *(const float2*)(src + 4);
            union { unsigned w[4]; bf16x8 v; } xf;
            xf.w[0] = cvt_pk_bf16(f0.x, f0.y);
            xf.w[1] = cvt_pk_bf16(f1.x, f1.y);
            xf.w[2] = cvt_pk_bf16(f2.x, f2.y);
            xf.w[3] = 0u;
            #pragma unroll
            for (int ct = 0; ct < 4; ++ct) {
                f32x4 c = __builtin_amdgcn_mfma_f32_16x16x32_bf16(
                    B1f[ct], xf.v, (f32x4){0.f, 0.f, 0.f, 0.f}, 0, 0, 0);
                float t0 = tanh_fused(c[0], b1s[ct][0]);
                float t1 = tanh_fused(c[1], b1s[ct][1]);
                float t2 = tanh_fused(c[2], b1s[ct][2]);
                float t3 = tanh_fused(c[3], b1s[ct][3]);
                uint2 dd;
                dd.x = cvt_pk_bf16(t0, t1);
                dd.y = cvt_pk_bf16(t2, t3);
                // row-major A-tile, 4 consecutive cols -> one 8B store
                *(uint2*)&u.a[(rt * 16 + c16) * LDA + colbase + ct * 16 + q * 4] = dd;
            }
        }
        __syncthreads();

        // ---- layer 2: (48x256)@(256x256), wave does 48 x 64, B in regs ----
        f32x4 acc[3][4];
        #pragma unroll
        for (int rt = 0; rt < 3; ++rt)
            #pragma unroll
            for (int ct = 0; ct < 4; ++ct) acc[rt][ct] = (f32x4){0.f, 0.f, 0.f, 0.f};

        #pragma unroll
        for (int kk = 0; kk < 8; ++kk) {
            bf16x8 Af[3];   // A layout: lane holds A[m=lane&15][k=q*8+j]
            #pragma unroll
            for (int rt = 0; rt < 3; ++rt)
                Af[rt] = *(const bf16x8*)&u.a[(rt * 16 + c16) * LDA + kk * 32 + q * 8];
            #pragma unroll
            for (int rt = 0; rt < 3; ++rt)
                #pragma unroll
                for (int ct = 0; ct < 4; ++ct)
                    acc[rt][ct] = __builtin_amdgcn_mfma_f32_16x16x32_bf16(
                        Af[rt], Bf[kk][ct], acc[rt][ct], 0, 0, 0);
        }
        __syncthreads();   // A-tile reads done before aliased ht writes

        // ---- epilogue: tanh -> bf16, transposed [col][row], packed dwords
        // C layout: col = colbase+ct*16+c16, row = rt*16+q*4+g
        #pragma unroll
        for (int ct = 0; ct < 4; ++ct) {
            const int col = colbase + ct * 16 + c16;
            #pragma unroll
            for (int rt = 0; rt < 3; ++rt) {
                float t0 = tanh_fused(acc[rt][ct][0], b2s[ct]);
                float t1 = tanh_fused(acc[rt][ct][1], b2s[ct]);
                float t2 = tanh_fused(acc[rt][ct][2], b2s[ct]);
                float t3 = tanh_fused(acc[rt][ct][3], b2s[ct]);
                const int row = rt * 16 + q * 4;   // even -> dword-aligned
                *(unsigned*)&u.ht[col * LDH + row]     = cvt_pk_bf16(t0, t1);
                *(unsigned*)&u.ht[col * LDH + row + 2] = cvt_pk_bf16(t2, t3);
            }
        }
        // NO barrier: thread tid reads col=tid, entirely written by its own
        // wave (colbase..colbase+63); in-wave lgkmcnt ordering suffices.

        // ---- mean over 6 neighbors: thread owns col=tid; 3 dwords/batch
        const int b0 = tile * TILE_B;
        #pragma unroll
        for (int bl = 0; bl < TILE_B; ++bl) {
            const unsigned* p = (const unsigned*)&u.ht[tid * LDH + bl * 6];
            float s = 0.f;
            #pragma unroll
            for (int d = 0; d < 3; ++d) {
                unsigned uu = p[d];
                s += __uint_as_float(uu << 16) + __uint_as_float(uu & 0xffff0000u);
            }
            out[(size_t)(b0 + bl) * HID + tid] = s * (1.0f / 6.0f);
        }
        __syncthreads();   // protect union reuse (next tile's u.a writes)
    }
}

extern "C" void kernel_launch(void* const* d_in, const int* in_sizes, int n_in,
                              void* d_out, int out_size, void* d_ws, size_t ws_size,
                              hipStream_t stream) {
    // inputs: 0 self_obs (unused), 1 obs, 2 W1, 3 b1, 4 W2, 5 b2, 6/7 scalars
    const float* obs = (const float*)d_in[1];
    const float* W1  = (const float*)d_in[2];
    const float* b1  = (const float*)d_in[3];
    const float* W2  = (const float*)d_in[4];
    const float* b2  = (const float*)d_in[5];
    float* outp = (float*)d_out;

    short* w2t = (short*)d_ws;                       // 131072 B
    short* w1t = (short*)((char*)d_ws + 131072);     // 16384 B

    prep<<<288, 256, 0, stream>>>(W1, W2, w1t, w2t);
    qenc_main<<<GRID_WG, 256, 0, stream>>>(obs, w1t, b1, w2t, b2, outp);
}